// Round 17
// baseline (417.938 us; speedup 1.0000x reference)
//
#include <hip/hip_runtime.h>

#define ALPHA_F 0.1f
#define EPS_F   1e-5f

typedef float    f32x4 __attribute__((ext_vector_type(4)));
typedef _Float16 h16x8 __attribute__((ext_vector_type(8)));
typedef _Float16 h16x2 __attribute__((ext_vector_type(2)));

__device__ __forceinline__ void gll16(const void* g, void* l)
{
    __builtin_amdgcn_global_load_lds(
        (const __attribute__((address_space(1))) void*)g,
        (__attribute__((address_space(3))) void*)l, 16, 0, 0);
}

// padded count per node: self-loop + edges, rounded up to multiple of 8
__device__ __forceinline__ int pad_cnt(int d) { return (d + 8) & ~7; }

// csr entry packed in 4B: low16 = src (N < 65536), high16 = fp16 weight bits
__device__ __forceinline__ unsigned pack_csr(int s, float w)
{
    _Float16 h = (_Float16)w;
    return (unsigned)(s & 0xFFFF)
         | ((unsigned)__builtin_bit_cast(unsigned short, h) << 16);
}

// ---------------------------------------------------------------------------
// W [K x 128] fp32 -> staging-interleaved fp16 layout
// ---------------------------------------------------------------------------
__global__ void convert_wstg(const float* __restrict__ W,
                             _Float16* __restrict__ Wstg, int K)
{
    int idx = blockIdx.x * 256 + threadIdx.x;
    if (idx < K * 128) {
        int k = idx >> 7, n = idx & 127;
        int i = k >> 5, kg = (k >> 3) & 3, j = k & 7;
        Wstg[(size_t)i * 4096 + (kg * 128 + n) * 8 + j] = (_Float16)W[idx];
    }
}

// ---------------------------------------------------------------------------
// GEMM2 (A fp16): out[M,128] = BN(A[M,K] @ W + bias) — m97-style staging.
// ---------------------------------------------------------------------------
__global__ __launch_bounds__(256) void gemm_stage_bn_h(
    const _Float16* __restrict__ Ah,
    const _Float16* __restrict__ Wstg,
    const float* __restrict__ bias,
    const float* __restrict__ gamma, const float* __restrict__ beta,
    const float* __restrict__ mean,  const float* __restrict__ var,
    _Float16* __restrict__ outh, int M, int K)
{
    __shared__ __align__(16) char Abuf[2][8192];
    __shared__ __align__(16) char Wbuf[2][8192];

    const int t   = threadIdx.x;
    const int w   = t >> 6;
    const int l   = t & 63;
    const int l15 = l & 15;
    const int lk  = l >> 4;
    const int bm  = blockIdx.x * 64;
    const int nk  = K >> 5;
    const int row = w * 16 + l15;

    f32x4 acc[8];
#pragma unroll
    for (int f = 0; f < 8; ++f) acc[f] = (f32x4){0.f, 0.f, 0.f, 0.f};

    auto stage = [&](int buf, int i) {
        const char* wsrc = (const char*)Wstg + (size_t)i * 8192;
#pragma unroll
        for (int c = 0; c < 2; ++c) {
            const int base = w * 128 + c * 64;
            gll16(wsrc + (size_t)(base + l) * 16, &Wbuf[buf][base * 16]);
        }
        const int base = w * 64;
        const int sl   = base + l;
        const int r    = sl >> 2;
        const int ch   = (sl & 3) ^ (r & 3);
        int gr = bm + r; gr = (gr < M) ? gr : (M - 1);
        const char* src = (const char*)Ah + ((size_t)gr * K + i * 32) * 2
                          + (size_t)ch * 16;
        gll16(src, &Abuf[buf][base * 16]);
    };

    auto compute = [&](int buf) {
        h16x8 a = *(const h16x8*)&Abuf[buf][(row * 4 + (lk ^ (row & 3))) * 16];
#pragma unroll
        for (int f = 0; f < 8; ++f) {
            h16x8 b = *(const h16x8*)&Wbuf[buf][(lk * 128 + f * 16 + l15) * 16];
            acc[f] = __builtin_amdgcn_mfma_f32_16x16x32_f16(a, b, acc[f], 0, 0, 0);
        }
    };

    stage(0, 0);
    for (int i = 0; i < nk; ++i) {
        __syncthreads();
        if (i + 1 < nk) stage((i + 1) & 1, i + 1);
        compute(i & 1);
    }

#pragma unroll
    for (int f = 0; f < 8; ++f) {
        const int col = f * 16 + l15;
        float s  = gamma[col] * rsqrtf(var[col] + EPS_F);
        float sh = beta[col] - mean[col] * s;
        float bb = bias[col];
#pragma unroll
        for (int rr = 0; rr < 4; ++rr) {
            int rg = bm + w * 16 + lk * 4 + rr;
            if (rg < M)
                outh[(size_t)rg * 128 + col] =
                    (_Float16)((acc[f][rr] + bb) * s + sh);
        }
    }
}

// ---------------------------------------------------------------------------
// FUSED: blocks [0,GB) = GEMM1; blocks [GB,..) = XCD-PARTITIONED scatter.
// Scatter: block's XCD = blockIdx.x & 7 (round-robin dispatch, T1/m192);
// it only handles edges whose dst is in its XCD's private node range
// -> CSR lines + cursor atomics stay in ONE L2 -> no cross-XCD writeback
// amplification. Each edge-list chunk is scanned by 8 consecutive blocks
// (one per XCD residue), so every edge is written exactly once.
// ---------------------------------------------------------------------------
__global__ __launch_bounds__(256) void fused_gemm1_scatter(
    const float* __restrict__ Af,
    const _Float16* __restrict__ Wstg,
    const float* __restrict__ bias,
    const float* __restrict__ gamma, const float* __restrict__ beta,
    const float* __restrict__ mean,  const float* __restrict__ var,
    _Float16* __restrict__ outh, int M, int K, int GB, int N,
    const int* __restrict__ src, const int* __restrict__ dst, int E, int SC,
    const float* __restrict__ dinv, int* __restrict__ cursor,
    unsigned* __restrict__ csr4)
{
    __shared__ __align__(16) char Abuf[2][8192];
    __shared__ __align__(16) char Wbuf[2][8192];

    if (blockIdx.x >= GB) {
        // ---- XCD-partitioned scatter branch ----
        const int xcd  = (int)(blockIdx.x & 7);
        const int nper = (N + 7) >> 3;
        const int lo   = xcd * nper;
        const int hi   = min(lo + nper, N);
        const int cid  = (int)(blockIdx.x - GB) >> 3;   // chunk id
        for (int e = cid * 256 + (int)threadIdx.x; e < E; e += SC * 256) {
            int d = dst[e];
            if (d >= lo && d < hi) {
                int s = src[e];
                int pos = atomicAdd(&cursor[d], 1);
                csr4[pos] = pack_csr(s, dinv[s] * dinv[d]);
            }
        }
        return;
    }

    // ---- GEMM1 branch (A fp32, relu, out fp16) ----
    const int t   = threadIdx.x;
    const int w   = t >> 6;
    const int l   = t & 63;
    const int l15 = l & 15;
    const int lk  = l >> 4;
    const int bm  = blockIdx.x * 64;
    const int nk  = K >> 5;
    const int row = w * 16 + l15;

    f32x4 acc[8];
#pragma unroll
    for (int f = 0; f < 8; ++f) acc[f] = (f32x4){0.f, 0.f, 0.f, 0.f};

    auto stage = [&](int buf, int i) {
        const char* wsrc = (const char*)Wstg + (size_t)i * 8192;
#pragma unroll
        for (int c = 0; c < 2; ++c) {
            const int base = w * 128 + c * 64;
            gll16(wsrc + (size_t)(base + l) * 16, &Wbuf[buf][base * 16]);
        }
#pragma unroll
        for (int c = 0; c < 2; ++c) {
            const int base = w * 128 + c * 64;
            const int sl   = base + l;
            const int r    = sl >> 3;
            const int ch   = (sl & 7) ^ (r & 7);
            int gr = bm + r; gr = (gr < M) ? gr : (M - 1);
            const char* srcp = (const char*)Af + ((size_t)gr * K + i * 32) * 4
                               + (size_t)ch * 16;
            gll16(srcp, &Abuf[buf][base * 16]);
        }
    };

    auto compute = [&](int buf) {
        f32x4 a0 = *(const f32x4*)&Abuf[buf][(row * 8 + ((2 * lk)     ^ (row & 7))) * 16];
        f32x4 a1 = *(const f32x4*)&Abuf[buf][(row * 8 + ((2 * lk + 1) ^ (row & 7))) * 16];
        h16x8 a;
#pragma unroll
        for (int j = 0; j < 4; ++j) {
            a[j]     = (_Float16)a0[j];
            a[4 + j] = (_Float16)a1[j];
        }
#pragma unroll
        for (int f = 0; f < 8; ++f) {
            h16x8 b = *(const h16x8*)&Wbuf[buf][(lk * 128 + f * 16 + l15) * 16];
            acc[f] = __builtin_amdgcn_mfma_f32_16x16x32_f16(a, b, acc[f], 0, 0, 0);
        }
    };

    stage(0, 0);
    for (int i = 0; i < nk; ++i) {
        __syncthreads();
        if (i + 1 < nk) stage((i + 1) & 1, i + 1);
        compute(i & 1);
    }

#pragma unroll
    for (int f = 0; f < 8; ++f) {
        const int col = f * 16 + l15;
        float s  = gamma[col] * rsqrtf(var[col] + EPS_F);
        float sh = beta[col] - mean[col] * s;
        float bb = bias[col];
#pragma unroll
        for (int rr = 0; rr < 4; ++rr) {
            int rg = bm + w * 16 + lk * 4 + rr;
            if (rg < M) {
                float v = fmaxf(acc[f][rr] + bb, 0.f);   // relu
                outh[(size_t)rg * 128 + col] = (_Float16)(v * s + sh);
            }
        }
    }
}

// ---------------------------------------------------------------------------
// Graph preprocessing
// ---------------------------------------------------------------------------
#define DEG_CHUNKS 256   // deg blocks = 8 * DEG_CHUNKS

// XCD-partitioned degree count: atomics stay in local L2 (same trick).
__global__ void count_deg(const int* __restrict__ dst, int E,
                          int* __restrict__ deg, int N)
{
    const int xcd  = (int)(blockIdx.x & 7);
    const int nper = (N + 7) >> 3;
    const int lo   = xcd * nper;
    const int hi   = min(lo + nper, N);
    const int cid  = (int)(blockIdx.x >> 3);
    for (int e = cid * 256 + (int)threadIdx.x; e < E; e += DEG_CHUNKS * 256) {
        int d = dst[e];
        if (d >= lo && d < hi) atomicAdd(&deg[d], 1);
    }
}

__global__ __launch_bounds__(256) void scan_block_sums(
    const int* __restrict__ deg, int* __restrict__ bsum, int N)
{
    __shared__ int sh[256];
    const int t  = threadIdx.x;
    const int i0 = blockIdx.x * 1024 + t * 4;
    int s = 0;
    if (i0 + 3 < N) {
        int4 d4 = *(const int4*)(deg + i0);
        s = pad_cnt(d4.x) + pad_cnt(d4.y) + pad_cnt(d4.z) + pad_cnt(d4.w);
    } else {
#pragma unroll
        for (int j = 0; j < 4; ++j)
            if (i0 + j < N) s += pad_cnt(deg[i0 + j]);
    }
    sh[t] = s;
    __syncthreads();
#pragma unroll
    for (int d = 128; d > 0; d >>= 1) {
        if (t < d) sh[t] += sh[t + d];
        __syncthreads();
    }
    if (t == 0) bsum[blockIdx.x] = sh[0];
}

__global__ __launch_bounds__(256) void scan_offsets(
    const int* __restrict__ deg, const int* __restrict__ bsum,
    int* __restrict__ offs, int* __restrict__ cursor,
    float* __restrict__ dinv, int N, int B)
{
    __shared__ int sh[256];
    __shared__ int sbase;
    const int b = blockIdx.x, t = threadIdx.x;

    int v = (t < b && t < B) ? bsum[t] : 0;
    sh[t] = v;
    __syncthreads();
#pragma unroll
    for (int d = 128; d > 0; d >>= 1) {
        if (t < d) sh[t] += sh[t + d];
        __syncthreads();
    }
    if (t == 0) sbase = sh[0];
    __syncthreads();

    const int i0 = b * 1024 + t * 4;
    int c[4], s = 0;
#pragma unroll
    for (int j = 0; j < 4; ++j) {
        int i = i0 + j;
        c[j] = (i < N) ? pad_cnt(deg[i]) : 0;
        s += c[j];
    }
    sh[t] = s;
    __syncthreads();
    for (int d = 1; d < 256; d <<= 1) {
        int o = (t >= d) ? sh[t - d] : 0;
        __syncthreads();
        sh[t] += o;
        __syncthreads();
    }
    int run = sbase + sh[t] - s;
#pragma unroll
    for (int j = 0; j < 4; ++j) {
        int i = i0 + j;
        if (i < N) {
            offs[i]   = run;
            cursor[i] = run;
            dinv[i]   = rsqrtf((float)(deg[i] + 1));
            run += c[j];
        }
    }
    if (b == B - 1 && t == 255) offs[N] = run;
}

__global__ void fill_self_pad(const int* __restrict__ offs, const int* __restrict__ deg,
                              const float* __restrict__ dinv,
                              unsigned* __restrict__ csr4, int N)
{
    int i = blockIdx.x * 256 + threadIdx.x;
    if (i < N) {
        int base = offs[i], d = deg[i], end = offs[i + 1];
        float di = dinv[i];
        csr4[base + d] = pack_csr(i, di * di);
        for (int p = base + d + 1; p < end; ++p)
            csr4[p] = pack_csr(i, 0.f);
    }
}

// ---------------------------------------------------------------------------
// One APPNP step (fp16 features): nxt = (1-a)*(A_hat @ cur) + a*h0.
// R13/R16 structure (measured optimum): persistent 8192 waves; four 16-lane
// groups; group g owns edges e+2g, e+2g+1 (one uint2/group/iter, 4B CSR);
// packed fp16 FMA; butterfly fp32 combine; step 10 writes fp32 d_out.
// ---------------------------------------------------------------------------
#define NWAVES 8192

__global__ __launch_bounds__(256) void appnp_step(
    const _Float16* __restrict__ cur, const _Float16* __restrict__ h0,
    const int* __restrict__ offs, const unsigned* __restrict__ csr4,
    _Float16* __restrict__ nxt, float* __restrict__ fout, int N)
{
    const int wv0  = __builtin_amdgcn_readfirstlane(
                        (int)((blockIdx.x * 256u + threadIdx.x) >> 6));
    const int lane = (int)(threadIdx.x & 63u);
    const int g    = lane >> 4;          // group 0..3
    const int fl   = (lane & 15) * 8;    // feature offset

    for (int i = wv0; i < N; i += NWAVES) {
        int e   = offs[i];
        int end = offs[i + 1];

        h16x2 acc[4];
#pragma unroll
        for (int j = 0; j < 4; ++j) acc[j] = (h16x2){(_Float16)0, (_Float16)0};

        uint2 m = *(const uint2*)(csr4 + e + 2 * g);
        h16x8 vA = *(const h16x8*)(cur + (size_t)(m.x & 0xFFFFu) * 128 + fl);
        h16x8 vB = *(const h16x8*)(cur + (size_t)(m.y & 0xFFFFu) * 128 + fl);

        for (e += 8; e < end; e += 8) {
            uint2 m2 = *(const uint2*)(csr4 + e + 2 * g);
            h16x8 vA2 = *(const h16x8*)(cur + (size_t)(m2.x & 0xFFFFu) * 128 + fl);
            h16x8 vB2 = *(const h16x8*)(cur + (size_t)(m2.y & 0xFFFFu) * 128 + fl);
            _Float16 ha = __builtin_bit_cast(_Float16, (unsigned short)(m.x >> 16));
            _Float16 hb = __builtin_bit_cast(_Float16, (unsigned short)(m.y >> 16));
            h16x2 wa = (h16x2){ha, ha}, wb = (h16x2){hb, hb};
#pragma unroll
            for (int j = 0; j < 4; ++j) {
                h16x2 va = (h16x2){vA[2 * j], vA[2 * j + 1]};
                h16x2 vb = (h16x2){vB[2 * j], vB[2 * j + 1]};
                acc[j] = __builtin_elementwise_fma(wa, va, acc[j]);
                acc[j] = __builtin_elementwise_fma(wb, vb, acc[j]);
            }
            m = m2; vA = vA2; vB = vB2;
        }
        {   // tail window
            _Float16 ha = __builtin_bit_cast(_Float16, (unsigned short)(m.x >> 16));
            _Float16 hb = __builtin_bit_cast(_Float16, (unsigned short)(m.y >> 16));
            h16x2 wa = (h16x2){ha, ha}, wb = (h16x2){hb, hb};
#pragma unroll
            for (int j = 0; j < 4; ++j) {
                h16x2 va = (h16x2){vA[2 * j], vA[2 * j + 1]};
                h16x2 vb = (h16x2){vB[2 * j], vB[2 * j + 1]};
                acc[j] = __builtin_elementwise_fma(wa, va, acc[j]);
                acc[j] = __builtin_elementwise_fma(wb, vb, acc[j]);
            }
        }

        float o[8];
#pragma unroll
        for (int j = 0; j < 4; ++j) {
            o[2 * j]     = (float)acc[j][0];
            o[2 * j + 1] = (float)acc[j][1];
        }
#pragma unroll
        for (int j = 0; j < 8; ++j) {
            o[j] += __shfl_xor(o[j], 16);
            o[j] += __shfl_xor(o[j], 32);
        }

        if (lane < 16) {
            h16x8 hv = *(const h16x8*)(h0 + (size_t)i * 128 + fl);
#pragma unroll
            for (int j = 0; j < 8; ++j)
                o[j] = ALPHA_F * (float)hv[j] + (1.f - ALPHA_F) * o[j];
            if (fout) {
                f32x4 o0, o1;
#pragma unroll
                for (int j = 0; j < 4; ++j) { o0[j] = o[j]; o1[j] = o[4 + j]; }
                *(f32x4*)(fout + (size_t)i * 128 + fl)     = o0;
                *(f32x4*)(fout + (size_t)i * 128 + fl + 4) = o1;
            } else {
                h16x8 o16;
#pragma unroll
                for (int j = 0; j < 8; ++j) o16[j] = (_Float16)o[j];
                *(h16x8*)(nxt + (size_t)i * 128 + fl) = o16;
            }
        }
    }
}

// ---------------------------------------------------------------------------
static inline size_t align_up(size_t x) { return (x + 255) & ~(size_t)255; }

extern "C" void kernel_launch(void* const* d_in, const int* in_sizes, int n_in,
                              void* d_out, int out_size, void* d_ws, size_t ws_size,
                              hipStream_t stream)
{
    const float* x   = (const float*)d_in[0];
    const int*   ei  = (const int*)d_in[1];
    const float* W1  = (const float*)d_in[2];
    const float* b1  = (const float*)d_in[3];
    const float* g1  = (const float*)d_in[4];
    const float* be1 = (const float*)d_in[5];
    const float* m1  = (const float*)d_in[6];
    const float* v1  = (const float*)d_in[7];
    const float* W2  = (const float*)d_in[8];
    const float* b2  = (const float*)d_in[9];
    const float* g2  = (const float*)d_in[10];
    const float* be2 = (const float*)d_in[11];
    const float* m2  = (const float*)d_in[12];
    const float* v2  = (const float*)d_in[13];

    const int N = in_sizes[0] / 512;   // 50000  (< 65536: u16 src packing ok)
    const int E = in_sizes[1] / 2;     // 800000
    const int* src = ei;
    const int* dst = ei + E;
    const int CSR_CAP = E + 8 * N;     // 4B entries
    const int NB = (N + 1023) / 1024;  // 49
    const int GB = (N + 63) / 64;      // GEMM1 blocks (782)
    const int SC = 1024;               // scatter chunks; blocks = 8*SC

    char* ws = (char*)d_ws;
    size_t off = 0;
    _Float16* hAh = (_Float16*)(ws + off); off += align_up((size_t)N * 128 * 2);
    _Float16* h0h = (_Float16*)(ws + off); off += align_up((size_t)N * 128 * 2);
    _Float16* p0  = (_Float16*)(ws + off); off += align_up((size_t)N * 128 * 2);
    _Float16* p1  = (_Float16*)(ws + off); off += align_up((size_t)N * 128 * 2);
    int*    deg  = (int*)(ws + off);    off += align_up((size_t)N * 4);
    float*  dinv = (float*)(ws + off);  off += align_up((size_t)N * 4);
    int*    offs = (int*)(ws + off);    off += align_up((size_t)(N + 1) * 4);
    int*    curs = (int*)(ws + off);    off += align_up((size_t)N * 4);
    int*    bsum = (int*)(ws + off);    off += align_up((size_t)256 * 4);
    unsigned* csr4 = (unsigned*)(ws + off); off += align_up((size_t)CSR_CAP * 4);
    _Float16* w1s = (_Float16*)(ws + off); off += align_up((size_t)512 * 128 * 2);
    _Float16* w2s = (_Float16*)(ws + off); off += align_up((size_t)128 * 128 * 2);

    // --- graph preprocessing (degree + offsets) ---
    hipMemsetAsync(deg, 0, (size_t)N * 4, stream);
    count_deg<<<8 * DEG_CHUNKS, 256, 0, stream>>>(dst, E, deg, N);
    scan_block_sums<<<NB, 256, 0, stream>>>(deg, bsum, N);
    scan_offsets<<<NB, 256, 0, stream>>>(deg, bsum, offs, curs, dinv, N, NB);

    // --- weights -> staging-interleaved fp16 ---
    convert_wstg<<<(512 * 128 + 255) / 256, 256, 0, stream>>>(W1, w1s, 512);
    convert_wstg<<<(128 * 128 + 255) / 256, 256, 0, stream>>>(W2, w2s, 128);

    // --- FUSED: GEMM1 (hAh = BN1(relu(x@W1+b1)))  ||  XCD-scatter ---
    fused_gemm1_scatter<<<GB + 8 * SC, 256, 0, stream>>>(
        x, w1s, b1, g1, be1, m1, v1, hAh, N, 512, GB, N,
        src, dst, E, SC, dinv, curs, csr4);

    // --- self-loops + pads; GEMM2: h0h = BN2(hAh@W2+b2) ---
    fill_self_pad<<<(N + 255) / 256, 256, 0, stream>>>(offs, deg, dinv, csr4, N);
    gemm_stage_bn_h<<<GB, 256, 0, stream>>>(
        hAh, w2s, b2, g2, be2, m2, v2, h0h, N, 128);

    // --- 10 propagation steps (fp16 ping-pong); step 10 writes fp32 d_out ---
    const _Float16* cur = h0h;
    for (int k = 0; k < 10; ++k) {
        _Float16* nxt = (k & 1) ? p1 : p0;
        float* fo = (k == 9) ? (float*)d_out : nullptr;
        appnp_step<<<NWAVES / 4, 256, 0, stream>>>(
            cur, h0h, offs, csr4, nxt, fo, N);
        cur = nxt;
    }

    (void)n_in; (void)out_size; (void)ws_size;
}

// Round 18
// 398.404 us; speedup vs baseline: 1.0490x; 1.0490x over previous
//
#include <hip/hip_runtime.h>

#define ALPHA_F 0.1f
#define EPS_F   1e-5f

typedef float    f32x4 __attribute__((ext_vector_type(4)));
typedef _Float16 h16x8 __attribute__((ext_vector_type(8)));
typedef _Float16 h16x2 __attribute__((ext_vector_type(2)));

__device__ __forceinline__ void gll16(const void* g, void* l)
{
    __builtin_amdgcn_global_load_lds(
        (const __attribute__((address_space(1))) void*)g,
        (__attribute__((address_space(3))) void*)l, 16, 0, 0);
}

// padded count per node: self-loop + edges, rounded up to multiple of 8
__device__ __forceinline__ int pad_cnt(int d) { return (d + 8) & ~7; }

// csr entry packed in 4B: low16 = src (N < 65536), high16 = fp16 weight bits
__device__ __forceinline__ unsigned pack_csr(int s, float w)
{
    _Float16 h = (_Float16)w;
    return (unsigned)(s & 0xFFFF)
         | ((unsigned)__builtin_bit_cast(unsigned short, h) << 16);
}

// ---------------------------------------------------------------------------
// FUSED prep: blocks [0,CB) count_deg; [CB,CB+256) convert W1; rest W2.
// All independent — grid-concat overlaps the atomics with the converts.
// ---------------------------------------------------------------------------
__global__ void prep_deg_weights(const int* __restrict__ dst, int E, int CB,
                                 int* __restrict__ deg,
                                 const float* __restrict__ W1,
                                 _Float16* __restrict__ W1s,
                                 const float* __restrict__ W2,
                                 _Float16* __restrict__ W2s)
{
    int b = (int)blockIdx.x;
    if (b < CB) {
        int e = b * 256 + (int)threadIdx.x;
        if (e < E) atomicAdd(&deg[dst[e]], 1);
        return;
    }
    b -= CB;
    const float* W;
    _Float16* Ws;
    int K;
    if (b < 256) { W = W1; Ws = W1s; K = 512; }
    else         { W = W2; Ws = W2s; K = 128; b -= 256; }
    int idx = b * 256 + (int)threadIdx.x;
    if (idx < K * 128) {
        int k = idx >> 7, n = idx & 127;
        int i = k >> 5, kg = (k >> 3) & 3, j = k & 7;
        Ws[(size_t)i * 4096 + (kg * 128 + n) * 8 + j] = (_Float16)W[idx];
    }
}

// ---------------------------------------------------------------------------
// FUSED: blocks [0,GB) = GEMM2 (A fp16, BN, out fp16); blocks [GB,..) =
// fill_self_pad. Both depend only on scatter+scan; fill hides under MFMA.
// ---------------------------------------------------------------------------
__global__ __launch_bounds__(256) void fused_gemm2_fill(
    const _Float16* __restrict__ Ah,
    const _Float16* __restrict__ Wstg,
    const float* __restrict__ bias,
    const float* __restrict__ gamma, const float* __restrict__ beta,
    const float* __restrict__ mean,  const float* __restrict__ var,
    _Float16* __restrict__ outh, int M, int K, int GB,
    const int* __restrict__ offs, const int* __restrict__ deg,
    const float* __restrict__ dinv, unsigned* __restrict__ csr4)
{
    __shared__ __align__(16) char Abuf[2][8192];
    __shared__ __align__(16) char Wbuf[2][8192];

    if (blockIdx.x >= GB) {
        // ---- fill_self_pad branch ----
        int i = (int)(blockIdx.x - GB) * 256 + (int)threadIdx.x;
        if (i < M) {
            int base = offs[i], d = deg[i], end = offs[i + 1];
            float di = dinv[i];
            csr4[base + d] = pack_csr(i, di * di);
            for (int p = base + d + 1; p < end; ++p)
                csr4[p] = pack_csr(i, 0.f);
        }
        return;
    }

    const int t   = threadIdx.x;
    const int w   = t >> 6;
    const int l   = t & 63;
    const int l15 = l & 15;
    const int lk  = l >> 4;
    const int bm  = blockIdx.x * 64;
    const int nk  = K >> 5;
    const int row = w * 16 + l15;

    f32x4 acc[8];
#pragma unroll
    for (int f = 0; f < 8; ++f) acc[f] = (f32x4){0.f, 0.f, 0.f, 0.f};

    auto stage = [&](int buf, int i) {
        const char* wsrc = (const char*)Wstg + (size_t)i * 8192;
#pragma unroll
        for (int c = 0; c < 2; ++c) {
            const int base = w * 128 + c * 64;
            gll16(wsrc + (size_t)(base + l) * 16, &Wbuf[buf][base * 16]);
        }
        const int base = w * 64;
        const int sl   = base + l;
        const int r    = sl >> 2;
        const int ch   = (sl & 3) ^ (r & 3);
        int gr = bm + r; gr = (gr < M) ? gr : (M - 1);
        const char* src = (const char*)Ah + ((size_t)gr * K + i * 32) * 2
                          + (size_t)ch * 16;
        gll16(src, &Abuf[buf][base * 16]);
    };

    auto compute = [&](int buf) {
        h16x8 a = *(const h16x8*)&Abuf[buf][(row * 4 + (lk ^ (row & 3))) * 16];
#pragma unroll
        for (int f = 0; f < 8; ++f) {
            h16x8 b = *(const h16x8*)&Wbuf[buf][(lk * 128 + f * 16 + l15) * 16];
            acc[f] = __builtin_amdgcn_mfma_f32_16x16x32_f16(a, b, acc[f], 0, 0, 0);
        }
    };

    stage(0, 0);
    for (int i = 0; i < nk; ++i) {
        __syncthreads();
        if (i + 1 < nk) stage((i + 1) & 1, i + 1);
        compute(i & 1);
    }

#pragma unroll
    for (int f = 0; f < 8; ++f) {
        const int col = f * 16 + l15;
        float s  = gamma[col] * rsqrtf(var[col] + EPS_F);
        float sh = beta[col] - mean[col] * s;
        float bb = bias[col];
#pragma unroll
        for (int rr = 0; rr < 4; ++rr) {
            int rg = bm + w * 16 + lk * 4 + rr;
            if (rg < M)
                outh[(size_t)rg * 128 + col] =
                    (_Float16)((acc[f][rr] + bb) * s + sh);
        }
    }
}

// ---------------------------------------------------------------------------
// FUSED: blocks [0,GB) = GEMM1 (A fp32, relu, out fp16); blocks [GB,..) =
// scatter_csr (R16 form — plain, non-partitioned; measured best).
// ---------------------------------------------------------------------------
__global__ __launch_bounds__(256) void fused_gemm1_scatter(
    const float* __restrict__ Af,
    const _Float16* __restrict__ Wstg,
    const float* __restrict__ bias,
    const float* __restrict__ gamma, const float* __restrict__ beta,
    const float* __restrict__ mean,  const float* __restrict__ var,
    _Float16* __restrict__ outh, int M, int K, int GB,
    const int* __restrict__ src, const int* __restrict__ dst, int E,
    const float* __restrict__ dinv, int* __restrict__ cursor,
    unsigned* __restrict__ csr4)
{
    __shared__ __align__(16) char Abuf[2][8192];
    __shared__ __align__(16) char Wbuf[2][8192];

    if (blockIdx.x >= GB) {
        int e = (int)(blockIdx.x - GB) * 256 + (int)threadIdx.x;
        if (e < E) {
            int s = src[e], d = dst[e];
            int pos = atomicAdd(&cursor[d], 1);
            csr4[pos] = pack_csr(s, dinv[s] * dinv[d]);
        }
        return;
    }

    const int t   = threadIdx.x;
    const int w   = t >> 6;
    const int l   = t & 63;
    const int l15 = l & 15;
    const int lk  = l >> 4;
    const int bm  = blockIdx.x * 64;
    const int nk  = K >> 5;
    const int row = w * 16 + l15;

    f32x4 acc[8];
#pragma unroll
    for (int f = 0; f < 8; ++f) acc[f] = (f32x4){0.f, 0.f, 0.f, 0.f};

    auto stage = [&](int buf, int i) {
        const char* wsrc = (const char*)Wstg + (size_t)i * 8192;
#pragma unroll
        for (int c = 0; c < 2; ++c) {
            const int base = w * 128 + c * 64;
            gll16(wsrc + (size_t)(base + l) * 16, &Wbuf[buf][base * 16]);
        }
#pragma unroll
        for (int c = 0; c < 2; ++c) {
            const int base = w * 128 + c * 64;
            const int sl   = base + l;
            const int r    = sl >> 3;
            const int ch   = (sl & 7) ^ (r & 7);
            int gr = bm + r; gr = (gr < M) ? gr : (M - 1);
            const char* srcp = (const char*)Af + ((size_t)gr * K + i * 32) * 4
                               + (size_t)ch * 16;
            gll16(srcp, &Abuf[buf][base * 16]);
        }
    };

    auto compute = [&](int buf) {
        f32x4 a0 = *(const f32x4*)&Abuf[buf][(row * 8 + ((2 * lk)     ^ (row & 7))) * 16];
        f32x4 a1 = *(const f32x4*)&Abuf[buf][(row * 8 + ((2 * lk + 1) ^ (row & 7))) * 16];
        h16x8 a;
#pragma unroll
        for (int j = 0; j < 4; ++j) {
            a[j]     = (_Float16)a0[j];
            a[4 + j] = (_Float16)a1[j];
        }
#pragma unroll
        for (int f = 0; f < 8; ++f) {
            h16x8 b = *(const h16x8*)&Wbuf[buf][(lk * 128 + f * 16 + l15) * 16];
            acc[f] = __builtin_amdgcn_mfma_f32_16x16x32_f16(a, b, acc[f], 0, 0, 0);
        }
    };

    stage(0, 0);
    for (int i = 0; i < nk; ++i) {
        __syncthreads();
        if (i + 1 < nk) stage((i + 1) & 1, i + 1);
        compute(i & 1);
    }

#pragma unroll
    for (int f = 0; f < 8; ++f) {
        const int col = f * 16 + l15;
        float s  = gamma[col] * rsqrtf(var[col] + EPS_F);
        float sh = beta[col] - mean[col] * s;
        float bb = bias[col];
#pragma unroll
        for (int rr = 0; rr < 4; ++rr) {
            int rg = bm + w * 16 + lk * 4 + rr;
            if (rg < M) {
                float v = fmaxf(acc[f][rr] + bb, 0.f);   // relu
                outh[(size_t)rg * 128 + col] = (_Float16)(v * s + sh);
            }
        }
    }
}

// ---------------------------------------------------------------------------
// Scans (unchanged)
// ---------------------------------------------------------------------------
__global__ __launch_bounds__(256) void scan_block_sums(
    const int* __restrict__ deg, int* __restrict__ bsum, int N)
{
    __shared__ int sh[256];
    const int t  = threadIdx.x;
    const int i0 = blockIdx.x * 1024 + t * 4;
    int s = 0;
    if (i0 + 3 < N) {
        int4 d4 = *(const int4*)(deg + i0);
        s = pad_cnt(d4.x) + pad_cnt(d4.y) + pad_cnt(d4.z) + pad_cnt(d4.w);
    } else {
#pragma unroll
        for (int j = 0; j < 4; ++j)
            if (i0 + j < N) s += pad_cnt(deg[i0 + j]);
    }
    sh[t] = s;
    __syncthreads();
#pragma unroll
    for (int d = 128; d > 0; d >>= 1) {
        if (t < d) sh[t] += sh[t + d];
        __syncthreads();
    }
    if (t == 0) bsum[blockIdx.x] = sh[0];
}

__global__ __launch_bounds__(256) void scan_offsets(
    const int* __restrict__ deg, const int* __restrict__ bsum,
    int* __restrict__ offs, int* __restrict__ cursor,
    float* __restrict__ dinv, int N, int B)
{
    __shared__ int sh[256];
    __shared__ int sbase;
    const int b = blockIdx.x, t = threadIdx.x;

    int v = (t < b && t < B) ? bsum[t] : 0;
    sh[t] = v;
    __syncthreads();
#pragma unroll
    for (int d = 128; d > 0; d >>= 1) {
        if (t < d) sh[t] += sh[t + d];
        __syncthreads();
    }
    if (t == 0) sbase = sh[0];
    __syncthreads();

    const int i0 = b * 1024 + t * 4;
    int c[4], s = 0;
#pragma unroll
    for (int j = 0; j < 4; ++j) {
        int i = i0 + j;
        c[j] = (i < N) ? pad_cnt(deg[i]) : 0;
        s += c[j];
    }
    sh[t] = s;
    __syncthreads();
    for (int d = 1; d < 256; d <<= 1) {
        int o = (t >= d) ? sh[t - d] : 0;
        __syncthreads();
        sh[t] += o;
        __syncthreads();
    }
    int run = sbase + sh[t] - s;
#pragma unroll
    for (int j = 0; j < 4; ++j) {
        int i = i0 + j;
        if (i < N) {
            offs[i]   = run;
            cursor[i] = run;
            dinv[i]   = rsqrtf((float)(deg[i] + 1));
            run += c[j];
        }
    }
    if (b == B - 1 && t == 255) offs[N] = run;
}

// ---------------------------------------------------------------------------
// One APPNP step (fp16 features) — R13/R16 measured optimum, untouched.
// ---------------------------------------------------------------------------
#define NWAVES 8192

__global__ __launch_bounds__(256) void appnp_step(
    const _Float16* __restrict__ cur, const _Float16* __restrict__ h0,
    const int* __restrict__ offs, const unsigned* __restrict__ csr4,
    _Float16* __restrict__ nxt, float* __restrict__ fout, int N)
{
    const int wv0  = __builtin_amdgcn_readfirstlane(
                        (int)((blockIdx.x * 256u + threadIdx.x) >> 6));
    const int lane = (int)(threadIdx.x & 63u);
    const int g    = lane >> 4;          // group 0..3
    const int fl   = (lane & 15) * 8;    // feature offset

    for (int i = wv0; i < N; i += NWAVES) {
        int e   = offs[i];
        int end = offs[i + 1];

        h16x2 acc[4];
#pragma unroll
        for (int j = 0; j < 4; ++j) acc[j] = (h16x2){(_Float16)0, (_Float16)0};

        uint2 m = *(const uint2*)(csr4 + e + 2 * g);
        h16x8 vA = *(const h16x8*)(cur + (size_t)(m.x & 0xFFFFu) * 128 + fl);
        h16x8 vB = *(const h16x8*)(cur + (size_t)(m.y & 0xFFFFu) * 128 + fl);

        for (e += 8; e < end; e += 8) {
            uint2 m2 = *(const uint2*)(csr4 + e + 2 * g);
            h16x8 vA2 = *(const h16x8*)(cur + (size_t)(m2.x & 0xFFFFu) * 128 + fl);
            h16x8 vB2 = *(const h16x8*)(cur + (size_t)(m2.y & 0xFFFFu) * 128 + fl);
            _Float16 ha = __builtin_bit_cast(_Float16, (unsigned short)(m.x >> 16));
            _Float16 hb = __builtin_bit_cast(_Float16, (unsigned short)(m.y >> 16));
            h16x2 wa = (h16x2){ha, ha}, wb = (h16x2){hb, hb};
#pragma unroll
            for (int j = 0; j < 4; ++j) {
                h16x2 va = (h16x2){vA[2 * j], vA[2 * j + 1]};
                h16x2 vb = (h16x2){vB[2 * j], vB[2 * j + 1]};
                acc[j] = __builtin_elementwise_fma(wa, va, acc[j]);
                acc[j] = __builtin_elementwise_fma(wb, vb, acc[j]);
            }
            m = m2; vA = vA2; vB = vB2;
        }
        {   // tail window
            _Float16 ha = __builtin_bit_cast(_Float16, (unsigned short)(m.x >> 16));
            _Float16 hb = __builtin_bit_cast(_Float16, (unsigned short)(m.y >> 16));
            h16x2 wa = (h16x2){ha, ha}, wb = (h16x2){hb, hb};
#pragma unroll
            for (int j = 0; j < 4; ++j) {
                h16x2 va = (h16x2){vA[2 * j], vA[2 * j + 1]};
                h16x2 vb = (h16x2){vB[2 * j], vB[2 * j + 1]};
                acc[j] = __builtin_elementwise_fma(wa, va, acc[j]);
                acc[j] = __builtin_elementwise_fma(wb, vb, acc[j]);
            }
        }

        float o[8];
#pragma unroll
        for (int j = 0; j < 4; ++j) {
            o[2 * j]     = (float)acc[j][0];
            o[2 * j + 1] = (float)acc[j][1];
        }
#pragma unroll
        for (int j = 0; j < 8; ++j) {
            o[j] += __shfl_xor(o[j], 16);
            o[j] += __shfl_xor(o[j], 32);
        }

        if (lane < 16) {
            h16x8 hv = *(const h16x8*)(h0 + (size_t)i * 128 + fl);
#pragma unroll
            for (int j = 0; j < 8; ++j)
                o[j] = ALPHA_F * (float)hv[j] + (1.f - ALPHA_F) * o[j];
            if (fout) {
                f32x4 o0, o1;
#pragma unroll
                for (int j = 0; j < 4; ++j) { o0[j] = o[j]; o1[j] = o[4 + j]; }
                *(f32x4*)(fout + (size_t)i * 128 + fl)     = o0;
                *(f32x4*)(fout + (size_t)i * 128 + fl + 4) = o1;
            } else {
                h16x8 o16;
#pragma unroll
                for (int j = 0; j < 8; ++j) o16[j] = (_Float16)o[j];
                *(h16x8*)(nxt + (size_t)i * 128 + fl) = o16;
            }
        }
    }
}

// ---------------------------------------------------------------------------
static inline size_t align_up(size_t x) { return (x + 255) & ~(size_t)255; }

extern "C" void kernel_launch(void* const* d_in, const int* in_sizes, int n_in,
                              void* d_out, int out_size, void* d_ws, size_t ws_size,
                              hipStream_t stream)
{
    const float* x   = (const float*)d_in[0];
    const int*   ei  = (const int*)d_in[1];
    const float* W1  = (const float*)d_in[2];
    const float* b1  = (const float*)d_in[3];
    const float* g1  = (const float*)d_in[4];
    const float* be1 = (const float*)d_in[5];
    const float* m1  = (const float*)d_in[6];
    const float* v1  = (const float*)d_in[7];
    const float* W2  = (const float*)d_in[8];
    const float* b2  = (const float*)d_in[9];
    const float* g2  = (const float*)d_in[10];
    const float* be2 = (const float*)d_in[11];
    const float* m2  = (const float*)d_in[12];
    const float* v2  = (const float*)d_in[13];

    const int N = in_sizes[0] / 512;   // 50000  (< 65536: u16 src packing ok)
    const int E = in_sizes[1] / 2;     // 800000
    const int* src = ei;
    const int* dst = ei + E;
    const int CSR_CAP = E + 8 * N;     // 4B entries
    const int NB = (N + 1023) / 1024;  // 49
    const int GB = (N + 63) / 64;      // GEMM blocks (782)
    const int CB = (E + 255) / 256;    // count/scatter blocks (3125)
    const int FB = (N + 255) / 256;    // fill blocks (196)

    char* ws = (char*)d_ws;
    size_t off = 0;
    _Float16* hAh = (_Float16*)(ws + off); off += align_up((size_t)N * 128 * 2);
    _Float16* h0h = (_Float16*)(ws + off); off += align_up((size_t)N * 128 * 2);
    _Float16* p0  = (_Float16*)(ws + off); off += align_up((size_t)N * 128 * 2);
    _Float16* p1  = (_Float16*)(ws + off); off += align_up((size_t)N * 128 * 2);
    int*    deg  = (int*)(ws + off);    off += align_up((size_t)N * 4);
    float*  dinv = (float*)(ws + off);  off += align_up((size_t)N * 4);
    int*    offs = (int*)(ws + off);    off += align_up((size_t)(N + 1) * 4);
    int*    curs = (int*)(ws + off);    off += align_up((size_t)N * 4);
    int*    bsum = (int*)(ws + off);    off += align_up((size_t)256 * 4);
    unsigned* csr4 = (unsigned*)(ws + off); off += align_up((size_t)CSR_CAP * 4);
    _Float16* w1s = (_Float16*)(ws + off); off += align_up((size_t)512 * 128 * 2);
    _Float16* w2s = (_Float16*)(ws + off); off += align_up((size_t)128 * 128 * 2);

    // --- fused prep: deg count || W1 convert || W2 convert ---
    hipMemsetAsync(deg, 0, (size_t)N * 4, stream);
    prep_deg_weights<<<CB + 256 + 64, 256, 0, stream>>>(
        dst, E, CB, deg, W1, w1s, W2, w2s);

    // --- scans (offs, cursor, dinv) ---
    scan_block_sums<<<NB, 256, 0, stream>>>(deg, bsum, N);
    scan_offsets<<<NB, 256, 0, stream>>>(deg, bsum, offs, curs, dinv, N, NB);

    // --- FUSED: GEMM1 (hAh = BN1(relu(x@W1+b1)))  ||  scatter_csr ---
    fused_gemm1_scatter<<<GB + CB, 256, 0, stream>>>(
        x, w1s, b1, g1, be1, m1, v1, hAh, N, 512, GB,
        src, dst, E, dinv, curs, csr4);

    // --- FUSED: GEMM2 (h0h = BN2(hAh@W2+b2))  ||  fill_self_pad ---
    fused_gemm2_fill<<<GB + FB, 256, 0, stream>>>(
        hAh, w2s, b2, g2, be2, m2, v2, h0h, N, 128, GB,
        offs, deg, dinv, csr4);

    // --- 10 propagation steps (fp16 ping-pong); step 10 writes fp32 d_out ---
    const _Float16* cur = h0h;
    for (int k = 0; k < 10; ++k) {
        _Float16* nxt = (k & 1) ? p1 : p0;
        float* fo = (k == 9) ? (float*)d_out : nullptr;
        appnp_step<<<NWAVES / 4, 256, 0, stream>>>(
            cur, h0h, offs, csr4, nxt, fo, N);
        cur = nxt;
    }

    (void)n_in; (void)out_size; (void)ws_size;
}